// Round 1
// baseline (352.177 us; speedup 1.0000x reference)
//
#include <hip/hip_runtime.h>
#include <hip/hip_cooperative_groups.h>

namespace cg = cooperative_groups;

// Problem: B=4, A=160000 anchors, G=64 gt boxes.
// outputs (concat flat): labels [B,A] f32, matched_gt_boxes [B,A,4] f32
constexpr int NB = 4;
constexpr int NA = 160000;
constexpr int NG = 64;
static_assert(NB * NG == 256, "zero phase assumes one thread per ws entry");

// Fused cooperative grid: 250 blocks per batch; each block owns
//   phase 1: 4 anchor chunks of 160 (j, j+250, j+500, j+750)
//   phase 2: the contiguous 640-anchor span [j*640, j*640+640)
constexpr int BPB  = 250;
constexpr int GRID = NB * BPB;   // 1000 blocks, 4/CU co-resident (bounds below)

// --- exact-rounding helpers -------------------------------------------------
__device__ __forceinline__ float box_area(float x0, float y0, float x1, float y1) {
#pragma clang fp contract(off)
    return (x1 - x0) * (y1 - y0);
}

// inter/denom with the exact op order of the numpy reference.
__device__ __forceinline__ void inter_denom(float gx0, float gy0, float gx1, float gy1, float garea,
                                            float ax0, float ay0, float ax1, float ay1, float aarea,
                                            float& inter, float& denom) {
#pragma clang fp contract(off)
    float ltx = fmaxf(gx0, ax0);
    float lty = fmaxf(gy0, ay0);
    float rbx = fminf(gx1, ax1);
    float rby = fminf(gy1, ay1);
    float w = fmaxf(rbx - ltx, 0.0f);
    float h = fmaxf(rby - lty, 0.0f);
    inter = w * h;
    float s = garea + aarea;        // numpy: area_gt + area_anchor
    denom = s - inter;
}

// exact comparison  i1/d1 > i2/d2  (all >= 0, d > 0), pure f32:
// 2-product via FMA gives the EXACT products p+e; ordering decided on the
// rounded products, ties broken on the exact tails. e cannot denormalize in
// our range (p >= ~2^-36 when nonzero), so this is the real-number ordering
// (replaces the f64 cross-multiply: no cvt_f64, no v_mul_f64).
__device__ __forceinline__ bool frac_gt(float i1, float d1, float i2, float d2) {
#pragma clang fp contract(off)
    float p1 = i1 * d2;
    float p2 = i2 * d1;
    float e1 = fmaf(i1, d2, -p1);
    float e2 = fmaf(i2, d1, -p2);
    return (p1 > p2) || ((p1 == p2) && (e1 > e2));
}

// Correctly-rounded f32 divide for our operand range (d in [16, ~5.7e4],
// n in [0, ~1.6e4], so v_div_scale would be an identity): this is exactly
// the numerical core LLVM emits for `/` (rcp + 1 NR + 2 residual FMA
// corrections) minus div_scale/div_fmas/div_fixup — bit-identical results,
// no implicit VCC dependency, so unrolled iterations pipeline freely.
__device__ __forceinline__ float div_rn(float n, float d) {
    float y = __builtin_amdgcn_rcpf(d);
    float e = fmaf(-d, y, 1.0f);
    y = fmaf(e, y, y);
    float q = n * y;
    float r = fmaf(-d, q, n);
    q = fmaf(r, y, q);
    float r2 = fmaf(-d, q, n);
    return fmaf(r2, y, q);
}

// --- fused cooperative kernel ----------------------------------------------
__global__ __launch_bounds__(256, 4) void fused(
        const float* __restrict__ anchors, const float* __restrict__ gts,
        const float* __restrict__ scores, const int* __restrict__ confs,
        int* __restrict__ highest /* ws, [NB*NG] float-as-int */,
        float* __restrict__ labels_out, float4* __restrict__ boxes_out) {
    __shared__ float4 sg[NG];        // gt box (per this block's b)
    __shared__ float2 sah[NG];       // {garea, highest} — filled after sync 2
    __shared__ float  ssc[NG];
    __shared__ int    scf[NG];
    __shared__ float  pi[4][NG], pd[4][NG];

    const int bx   = blockIdx.x;
    const int b    = bx / BPB;
    const int j    = bx - b * BPB;
    const int lane = threadIdx.x & 63;
    const int wid  = __builtin_amdgcn_readfirstlane(threadIdx.x >> 6);

    // stage per-b gt data once; LDS persists across grid syncs (co-resident)
    if (threadIdx.x < NG) {
        const int gi = threadIdx.x;
        sg[gi]  = reinterpret_cast<const float4*>(gts)[b * NG + gi];
        ssc[gi] = scores[b * NG + gi];
        scf[gi] = confs[b * NG + gi];
    }
    // zero the workspace through the coherent point (block 0, one entry/thread)
    if (bx == 0) {
        __hip_atomic_store(&highest[threadIdx.x], 0, __ATOMIC_RELAXED,
                           __HIP_MEMORY_SCOPE_AGENT);
    }
    cg::grid_group grid = cg::this_grid();
    grid.sync();                                   // ws zeroed everywhere

    // ---- phase 1: per-gt max over this block's 4 x 160 anchors -------------
    const float4* __restrict__ anc =
        reinterpret_cast<const float4*>(anchors) + (size_t)b * NA;
    float4 g = reinterpret_cast<const float4*>(gts)[b * NG + lane];
    float garea = box_area(g.x, g.y, g.z, g.w);

    float bi = 0.0f, bd = 1.0f;                    // best (inter, denom): q=0
#pragma unroll
    for (int cc = 0; cc < 4; ++cc) {
        const int base = (j + cc * BPB) * 160 + wid * 40;
#pragma unroll 8
        for (int i = 0; i < 40; ++i) {
            float4 a = anc[base + i];              // wave-uniform -> s_load
            float aarea = box_area(a.x, a.y, a.z, a.w);
            float inter, denom;
            inter_denom(g.x, g.y, g.z, g.w, garea, a.x, a.y, a.z, a.w, aarea,
                        inter, denom);
            if (frac_gt(inter, denom, bi, bd)) { bi = inter; bd = denom; }
        }
    }
    pi[wid][lane] = bi;
    pd[wid][lane] = bd;
    __syncthreads();
    if (threadIdx.x < NG) {
        float ci = pi[0][threadIdx.x], cd = pd[0][threadIdx.x];
#pragma unroll
        for (int wv = 1; wv < 4; ++wv) {
            float ni = pi[wv][threadIdx.x], nd = pd[wv][threadIdx.x];
            if (frac_gt(ni, nd, ci, cd)) { ci = ni; cd = nd; }
        }
        float m = div_rn(ci, cd);                  // same rounding as phase 2
        atomicMax(&highest[b * NG + threadIdx.x], __float_as_int(m));
    }

    grid.sync();                                   // highest is final

    if (threadIdx.x < NG) {
        const int gi = threadIdx.x;
        int hv = __hip_atomic_load(&highest[b * NG + gi], __ATOMIC_RELAXED,
                                   __HIP_MEMORY_SCOPE_AGENT);
        float4 gv = sg[gi];
        sah[gi] = make_float2(box_area(gv.x, gv.y, gv.z, gv.w),
                              __int_as_float(hv));
    }
    __syncthreads();

    // ---- phase 2: per-anchor assignment over span [j*640, j*640+640) -------
    const int base2 = j * 640;
    for (int ai = base2 + threadIdx.x; ai < base2 + 640; ai += 256) {
        float4 av = anc[ai];                       // per-lane coalesced load
        float aarea = box_area(av.x, av.y, av.z, av.w);

        float best = -1.0f;                        // all-zero row -> argmax 0
        int   matches = 0;
        bool  lowq = false;
#pragma unroll 4
        for (int gi = 0; gi < NG; ++gi) {
            float4 gb = sg[gi];                    // ds_read_b128 broadcast
            float2 ah = sah[gi];                   // ds_read_b64 broadcast
            float inter, denom;
            inter_denom(gb.x, gb.y, gb.z, gb.w, ah.x,
                        av.x, av.y, av.z, av.w, aarea, inter, denom);
            float v = div_rn(inter, denom);        // bit-exact IEEE quotient
            if (v > best) { best = v; matches = gi; }  // strict > keeps FIRST max
            lowq |= (v == ah.y);                   // bit-exact equality
        }

        int m    = (best < 0.3f) ? -1 : ((best < 0.7f) ? -2 : matches);
        int midx = lowq ? matches : m;
        int cl   = (midx < 0) ? 0 : midx;

        float4 mg = sg[cl];
        float  sc = ssc[cl];
        int    cf = scf[cl];

        bool pos = (midx >= 0);
        float lab = pos ? 1.0f : 0.0f;
        lab = fminf(lab, sc);
        if (midx == -1) lab = 0.0f;
        if (midx == -2) lab = -1.0f;
        if (sc < 1.0f && pos) lab = -1.0f;
        if (cf == 0 && pos) lab = -1.0f;

        labels_out[(size_t)b * NA + ai] = lab;
        boxes_out[(size_t)b * NA + ai] = mg;
    }
}

// --- legacy 3-dispatch fallback (known-passing), used only if the
// --- cooperative launch is rejected by the runtime/capture ------------------
__device__ __forceinline__ float iou_f(float gx0, float gy0, float gx1, float gy1, float garea,
                                       float ax0, float ay0, float ax1, float ay1, float aarea) {
    float inter, denom;
    inter_denom(gx0, gy0, gx1, gy1, garea, ax0, ay0, ax1, ay1, aarea, inter, denom);
    return inter / denom;
}

__global__ __launch_bounds__(256) void k_gt_highest(
        const float* __restrict__ anchors, const float* __restrict__ gts,
        float* __restrict__ highest /* [B*G], pre-zeroed */) {
    const int b = blockIdx.y;
    const int lane = threadIdx.x & 63;
    const int wid = __builtin_amdgcn_readfirstlane(threadIdx.x >> 6);

    const float4* __restrict__ gt4 = reinterpret_cast<const float4*>(gts) + b * NG;
    const float4* __restrict__ anc = reinterpret_cast<const float4*>(anchors) + (size_t)b * NA;

    float4 g = gt4[lane];
    float garea = box_area(g.x, g.y, g.z, g.w);

    const int base = blockIdx.x * 160 + wid * 40;
    float bi = 0.0f, bd = 1.0f;
#pragma unroll 8
    for (int i = 0; i < 40; ++i) {
        float4 a = anc[base + i];
        float aarea = box_area(a.x, a.y, a.z, a.w);
        float inter, denom;
        inter_denom(g.x, g.y, g.z, g.w, garea, a.x, a.y, a.z, a.w, aarea,
                    inter, denom);
        if (frac_gt(inter, denom, bi, bd)) { bi = inter; bd = denom; }
    }

    __shared__ float pi[4][NG], pd[4][NG];
    pi[wid][lane] = bi;
    pd[wid][lane] = bd;
    __syncthreads();
    if (threadIdx.x < NG) {
        float ci = pi[0][threadIdx.x], cd = pd[0][threadIdx.x];
#pragma unroll
        for (int wv = 1; wv < 4; ++wv) {
            float ni = pi[wv][threadIdx.x], nd = pd[wv][threadIdx.x];
            if (frac_gt(ni, nd, ci, cd)) { ci = ni; cd = nd; }
        }
        float m = ci / cd;
        atomicMax(reinterpret_cast<int*>(&highest[b * NG + threadIdx.x]),
                  __float_as_int(m));
    }
}

__global__ __launch_bounds__(256) void k_assign(
        const float* __restrict__ anchors, const float* __restrict__ gts,
        const float* __restrict__ scores, const int* __restrict__ confs,
        const float* __restrict__ highest,
        float* __restrict__ labels_out, float4* __restrict__ boxes_out) {
    __shared__ float4 sg[NG];
    __shared__ float2 sah[NG];
    __shared__ float ssc[NG];
    __shared__ int scf[NG];

    const int b = blockIdx.y;
    if (threadIdx.x < NG) {
        const int gi = threadIdx.x;
        float4 gv = reinterpret_cast<const float4*>(gts)[b * NG + gi];
        sg[gi] = gv;
        sah[gi] = make_float2(box_area(gv.x, gv.y, gv.z, gv.w),
                              highest[b * NG + gi]);
        ssc[gi] = scores[b * NG + gi];
        scf[gi] = confs[b * NG + gi];
    }
    __syncthreads();

    const int ai = blockIdx.x * 256 + threadIdx.x;
    const float4* __restrict__ anc = reinterpret_cast<const float4*>(anchors) + (size_t)b * NA;
    float4 av = anc[ai];
    float aarea = box_area(av.x, av.y, av.z, av.w);

    float best = -1.0f;
    int   matches = 0;
    bool  lowq = false;
#pragma unroll 4
    for (int g = 0; g < NG; ++g) {
        float4 gb = sg[g];
        float2 ah = sah[g];
        float v = iou_f(gb.x, gb.y, gb.z, gb.w, ah.x,
                        av.x, av.y, av.z, av.w, aarea);
        if (v > best) { best = v; matches = g; }
        lowq |= (v == ah.y);
    }

    int m    = (best < 0.3f) ? -1 : ((best < 0.7f) ? -2 : matches);
    int midx = lowq ? matches : m;
    int cl   = (midx < 0) ? 0 : midx;

    float4 mg = sg[cl];
    float  sc = ssc[cl];
    int    cf = scf[cl];

    bool pos = (midx >= 0);
    float lab = pos ? 1.0f : 0.0f;
    lab = fminf(lab, sc);
    if (midx == -1) lab = 0.0f;
    if (midx == -2) lab = -1.0f;
    if (sc < 1.0f && pos) lab = -1.0f;
    if (cf == 0 && pos) lab = -1.0f;

    labels_out[(size_t)b * NA + ai] = lab;
    boxes_out[(size_t)b * NA + ai] = mg;
}

extern "C" void kernel_launch(void* const* d_in, const int* in_sizes, int n_in,
                              void* d_out, int out_size, void* d_ws, size_t ws_size,
                              hipStream_t stream) {
    const float* anchors = (const float*)d_in[0];   // [B,A,4]
    const float* gts     = (const float*)d_in[1];   // [B,G,4]
    const float* scores  = (const float*)d_in[2];   // [B,G]
    const int*   confs   = (const int*)d_in[3];     // [B,G]

    float* labels_out = (float*)d_out;                              // [B,A]
    float4* boxes_out = (float4*)((float*)d_out + (size_t)NB * NA); // [B,A,4]
    int* highest_i = (int*)d_ws;                                    // [B*G]

    void* args[] = {(void*)&anchors, (void*)&gts, (void*)&scores, (void*)&confs,
                    (void*)&highest_i, (void*)&labels_out, (void*)&boxes_out};
    hipError_t err = hipLaunchCooperativeKernel(
        fused, dim3(GRID), dim3(256), args, 0u, stream);

    if (err != hipSuccess) {
        (void)hipGetLastError();   // clear error state, take the legacy path
        float* highest = (float*)d_ws;
        hipMemsetAsync(d_ws, 0, (size_t)NB * NG * sizeof(float), stream);
        dim3 g1(1000, NB), g2(625, NB), blk(256);
        k_gt_highest<<<g1, blk, 0, stream>>>(anchors, gts, highest);
        k_assign<<<g2, blk, 0, stream>>>(anchors, gts, scores, confs, highest,
                                         labels_out, boxes_out);
    }
}

// Round 2
// 156.055 us; speedup vs baseline: 2.2567x; 2.2567x over previous
//
#include <hip/hip_runtime.h>

// Problem: B=4, A=160000 anchors, G=64 gt boxes.
// outputs (concat flat): labels [B,A] f32, matched_gt_boxes [B,A,4] f32
constexpr int NB = 4;
constexpr int NA = 160000;
constexpr int NG = 64;

// Two-dispatch scheme: k_part writes per-block per-gt (inter,denom) partials
// (no atomics, no memset dispatch); k_assign2 reduces them in its prologue.
constexpr int P1  = 250;          // partial slots per (b,g)  -> ws = 512000 B
constexpr int APB = NA / P1;      // 640 anchors per k_part block
constexpr int APW = APB / 4;      // 160 anchors per wave (contiguous, s_load)

// --- exact-rounding helpers -------------------------------------------------
// contract(off): stop fma fusion that would change rounding vs numpy.
__device__ __forceinline__ float box_area(float x0, float y0, float x1, float y1) {
#pragma clang fp contract(off)
    return (x1 - x0) * (y1 - y0);
}

// inter/denom with the exact op order of the numpy reference; shared by both
// kernels so phase-1's deferred quotient is bit-identical to phase-2's.
__device__ __forceinline__ void inter_denom(float gx0, float gy0, float gx1, float gy1, float garea,
                                            float ax0, float ay0, float ax1, float ay1, float aarea,
                                            float& inter, float& denom) {
#pragma clang fp contract(off)
    float ltx = fmaxf(gx0, ax0);
    float lty = fmaxf(gy0, ay0);
    float rbx = fminf(gx1, ax1);
    float rby = fminf(gy1, ay1);
    float w = fmaxf(rbx - ltx, 0.0f);
    float h = fmaxf(rby - lty, 0.0f);
    inter = w * h;
    float s = garea + aarea;        // numpy: area_gt + area_anchor
    denom = s - inter;
}

// exact comparison  i1/d1 > i2/d2  (all >= 0, d > 0), pure f32:
// FMA two-product gives the EXACT products p+e; ordering decided on the
// rounded products, ties broken on the exact tails (real-number ordering).
// Harness-validated bit-exact in round 1 (absmax = 0.0).
__device__ __forceinline__ bool frac_gt(float i1, float d1, float i2, float d2) {
#pragma clang fp contract(off)
    float p1 = i1 * d2;
    float p2 = i2 * d1;
    float e1 = fmaf(i1, d2, -p1);
    float e2 = fmaf(i2, d1, -p2);
    return (p1 > p2) || ((p1 == p2) && (e1 > e2));
}

// Correctly-rounded f32 divide for our operand range (d in [16, ~5.7e4],
// n in [0, ~1.6e4]): the numerical core LLVM emits for `/` (rcp + NR + 2
// exact-residual FMA corrections) minus div_scale/div_fmas/div_fixup —
// bit-identical results (harness-validated round 1), and NO implicit VCC
// dependency, so unrolled iterations pipeline their divide chains freely.
__device__ __forceinline__ float div_rn(float n, float d) {
    float y = __builtin_amdgcn_rcpf(d);
    float e = fmaf(-d, y, 1.0f);
    y = fmaf(e, y, y);
    float q = n * y;
    float r = fmaf(-d, q, n);
    q = fmaf(r, y, q);
    float r2 = fmaf(-d, q, n);
    return fmaf(r2, y, q);
}

// --- kernel 1: per-block per-gt best (inter,denom) partials -----------------
// grid (P1, NB), block 256 = 4 waves. Wave w scans 160 CONTIGUOUS anchors
// [j*640 + w*160, +160) with wave-uniform s_load addresses, unroll 8 keeps
// 8 scalar loads in flight (the proven round-0 inner-loop shape).
__global__ __launch_bounds__(256) void k_part(
        const float* __restrict__ anchors, const float* __restrict__ gts,
        float2* __restrict__ part /* [NB][P1][NG] */) {
    const int b = blockIdx.y;
    const int j = blockIdx.x;
    const int lane = threadIdx.x & 63;
    const int wid = __builtin_amdgcn_readfirstlane(threadIdx.x >> 6);

    const float4* __restrict__ anc =
        reinterpret_cast<const float4*>(anchors) + (size_t)b * NA;
    float4 g = reinterpret_cast<const float4*>(gts)[b * NG + lane];
    float garea = box_area(g.x, g.y, g.z, g.w);

    const int base = j * APB + wid * APW;
    float bi = 0.0f, bd = 1.0f;                     // best (inter,denom): q=0
#pragma unroll 8
    for (int i = 0; i < APW; ++i) {
        float4 a = anc[base + i];                   // wave-uniform -> s_load
        float aarea = box_area(a.x, a.y, a.z, a.w);
        float inter, denom;
        inter_denom(g.x, g.y, g.z, g.w, garea, a.x, a.y, a.z, a.w, aarea,
                    inter, denom);
        if (frac_gt(inter, denom, bi, bd)) { bi = inter; bd = denom; }
    }

    __shared__ float pi[4][NG], pd[4][NG];
    pi[wid][lane] = bi;
    pd[wid][lane] = bd;
    __syncthreads();
    if (threadIdx.x < NG) {
        float ci = pi[0][threadIdx.x], cd = pd[0][threadIdx.x];
#pragma unroll
        for (int wv = 1; wv < 4; ++wv) {
            float ni = pi[wv][threadIdx.x], nd = pd[wv][threadIdx.x];
            if (frac_gt(ni, nd, ci, cd)) { ci = ni; cd = nd; }
        }
        // coalesced 64 x 8B store; layout [p][g] so k2's reduce is coalesced
        part[((size_t)b * P1 + j) * NG + threadIdx.x] = make_float2(ci, cd);
    }
}

// --- kernel 2: reduce partials + per-anchor match + labels ------------------
// grid (625, NB), block 256, ONE anchor per thread. Prologue reduces the 250
// partials per gt (all 256 threads: thread t owns gt t&63, chunk t>>6;
// [p][g] layout -> each wave's 64 lanes read 64 consecutive float2s).
__global__ __launch_bounds__(256) void k_assign2(
        const float* __restrict__ anchors, const float* __restrict__ gts,
        const float* __restrict__ scores, const int* __restrict__ confs,
        const float2* __restrict__ part,
        float* __restrict__ labels_out, float4* __restrict__ boxes_out) {
    __shared__ float4 sg[NG];       // gt box
    __shared__ float2 sah[NG];      // {garea, highest}
    __shared__ float  ssc[NG];
    __shared__ int    scf[NG];
    __shared__ float  rpi[4][NG], rpd[4][NG];

    const int b = blockIdx.y;
    if (threadIdx.x < NG) {
        const int gi = threadIdx.x;
        sg[gi]  = reinterpret_cast<const float4*>(gts)[b * NG + gi];
        ssc[gi] = scores[b * NG + gi];
        scf[gi] = confs[b * NG + gi];
    }

    {   // partial reduce: 256 threads, 62-63 coalesced L2-hit loads each
        const int gi = threadIdx.x & 63;
        const int c  = threadIdx.x >> 6;
        float ci = 0.0f, cd = 1.0f;
        for (int p = c; p < P1; p += 4) {
            float2 v = part[((size_t)b * P1 + p) * NG + gi];
            if (frac_gt(v.x, v.y, ci, cd)) { ci = v.x; cd = v.y; }
        }
        rpi[c][gi] = ci;
        rpd[c][gi] = cd;
    }
    __syncthreads();
    if (threadIdx.x < NG) {
        const int gi = threadIdx.x;
        float ci = rpi[0][gi], cd = rpd[0][gi];
#pragma unroll
        for (int wv = 1; wv < 4; ++wv) {
            float ni = rpi[wv][gi], nd = rpd[wv][gi];
            if (frac_gt(ni, nd, ci, cd)) { ci = ni; cd = nd; }
        }
        float4 gv = sg[gi];                         // written by this thread
        sah[gi] = make_float2(box_area(gv.x, gv.y, gv.z, gv.w),
                              div_rn(ci, cd));      // single rounded quotient
    }
    __syncthreads();

    const int ai = blockIdx.x * 256 + threadIdx.x;  // 0..159999
    const float4* __restrict__ anc =
        reinterpret_cast<const float4*>(anchors) + (size_t)b * NA;
    float4 av = anc[ai];
    float aarea = box_area(av.x, av.y, av.z, av.w);

    float best = -1.0f;             // all-zero row -> argmax 0 (first max)
    int   matches = 0;
    bool  lowq = false;
#pragma unroll 4
    for (int g = 0; g < NG; ++g) {
        float4 gb = sg[g];                          // ds_read_b128 broadcast
        float2 ah = sah[g];                         // ds_read_b64 broadcast
        float inter, denom;
        inter_denom(gb.x, gb.y, gb.z, gb.w, ah.x,
                    av.x, av.y, av.z, av.w, aarea, inter, denom);
        float v = div_rn(inter, denom);             // no VCC: chains pipeline
        if (v > best) { best = v; matches = g; }    // strict > keeps FIRST max
        lowq |= (v == ah.y);                        // bit-exact equality
    }

    int m    = (best < 0.3f) ? -1 : ((best < 0.7f) ? -2 : matches);
    int midx = lowq ? matches : m;
    int cl   = (midx < 0) ? 0 : midx;

    float4 mg = sg[cl];
    float  sc = ssc[cl];
    int    cf = scf[cl];

    bool pos = (midx >= 0);
    float lab = pos ? 1.0f : 0.0f;
    lab = fminf(lab, sc);
    if (midx == -1) lab = 0.0f;
    if (midx == -2) lab = -1.0f;
    if (sc < 1.0f && pos) lab = -1.0f;
    if (cf == 0 && pos) lab = -1.0f;

    labels_out[(size_t)b * NA + ai] = lab;
    boxes_out[(size_t)b * NA + ai] = mg;
}

// --- fallback: round-0 3-dispatch path (if ws is too small for partials) ----
__global__ __launch_bounds__(256) void k_gt_highest_fb(
        const float* __restrict__ anchors, const float* __restrict__ gts,
        float* __restrict__ highest /* [B*G], pre-zeroed */) {
    const int b = blockIdx.y;
    const int lane = threadIdx.x & 63;
    const int wid = __builtin_amdgcn_readfirstlane(threadIdx.x >> 6);

    const float4* __restrict__ anc =
        reinterpret_cast<const float4*>(anchors) + (size_t)b * NA;
    float4 g = reinterpret_cast<const float4*>(gts)[b * NG + lane];
    float garea = box_area(g.x, g.y, g.z, g.w);

    const int base = blockIdx.x * 160 + wid * 40;
    float bi = 0.0f, bd = 1.0f;
#pragma unroll 8
    for (int i = 0; i < 40; ++i) {
        float4 a = anc[base + i];
        float aarea = box_area(a.x, a.y, a.z, a.w);
        float inter, denom;
        inter_denom(g.x, g.y, g.z, g.w, garea, a.x, a.y, a.z, a.w, aarea,
                    inter, denom);
        if (frac_gt(inter, denom, bi, bd)) { bi = inter; bd = denom; }
    }

    __shared__ float pi[4][NG], pd[4][NG];
    pi[wid][lane] = bi;
    pd[wid][lane] = bd;
    __syncthreads();
    if (threadIdx.x < NG) {
        float ci = pi[0][threadIdx.x], cd = pd[0][threadIdx.x];
#pragma unroll
        for (int wv = 1; wv < 4; ++wv) {
            float ni = pi[wv][threadIdx.x], nd = pd[wv][threadIdx.x];
            if (frac_gt(ni, nd, ci, cd)) { ci = ni; cd = nd; }
        }
        atomicMax(reinterpret_cast<int*>(&highest[b * NG + threadIdx.x]),
                  __float_as_int(div_rn(ci, cd)));
    }
}

__global__ __launch_bounds__(256) void k_assign_fb(
        const float* __restrict__ anchors, const float* __restrict__ gts,
        const float* __restrict__ scores, const int* __restrict__ confs,
        const float* __restrict__ highest,
        float* __restrict__ labels_out, float4* __restrict__ boxes_out) {
    __shared__ float4 sg[NG];
    __shared__ float2 sah[NG];
    __shared__ float  ssc[NG];
    __shared__ int    scf[NG];

    const int b = blockIdx.y;
    if (threadIdx.x < NG) {
        const int gi = threadIdx.x;
        float4 gv = reinterpret_cast<const float4*>(gts)[b * NG + gi];
        sg[gi] = gv;
        sah[gi] = make_float2(box_area(gv.x, gv.y, gv.z, gv.w),
                              highest[b * NG + gi]);
        ssc[gi] = scores[b * NG + gi];
        scf[gi] = confs[b * NG + gi];
    }
    __syncthreads();

    const int ai = blockIdx.x * 256 + threadIdx.x;
    const float4* __restrict__ anc =
        reinterpret_cast<const float4*>(anchors) + (size_t)b * NA;
    float4 av = anc[ai];
    float aarea = box_area(av.x, av.y, av.z, av.w);

    float best = -1.0f;
    int   matches = 0;
    bool  lowq = false;
#pragma unroll 4
    for (int g = 0; g < NG; ++g) {
        float4 gb = sg[g];
        float2 ah = sah[g];
        float inter, denom;
        inter_denom(gb.x, gb.y, gb.z, gb.w, ah.x,
                    av.x, av.y, av.z, av.w, aarea, inter, denom);
        float v = div_rn(inter, denom);
        if (v > best) { best = v; matches = g; }
        lowq |= (v == ah.y);
    }

    int m    = (best < 0.3f) ? -1 : ((best < 0.7f) ? -2 : matches);
    int midx = lowq ? matches : m;
    int cl   = (midx < 0) ? 0 : midx;

    float4 mg = sg[cl];
    float  sc = ssc[cl];
    int    cf = scf[cl];

    bool pos = (midx >= 0);
    float lab = pos ? 1.0f : 0.0f;
    lab = fminf(lab, sc);
    if (midx == -1) lab = 0.0f;
    if (midx == -2) lab = -1.0f;
    if (sc < 1.0f && pos) lab = -1.0f;
    if (cf == 0 && pos) lab = -1.0f;

    labels_out[(size_t)b * NA + ai] = lab;
    boxes_out[(size_t)b * NA + ai] = mg;
}

extern "C" void kernel_launch(void* const* d_in, const int* in_sizes, int n_in,
                              void* d_out, int out_size, void* d_ws, size_t ws_size,
                              hipStream_t stream) {
    const float* anchors = (const float*)d_in[0];   // [B,A,4]
    const float* gts     = (const float*)d_in[1];   // [B,G,4]
    const float* scores  = (const float*)d_in[2];   // [B,G]
    const int*   confs   = (const int*)d_in[3];     // [B,G]

    float* labels_out = (float*)d_out;                              // [B,A]
    float4* boxes_out = (float4*)((float*)d_out + (size_t)NB * NA); // [B,A,4]

    const size_t need = (size_t)NB * P1 * NG * sizeof(float2);      // 512 KB
    if (ws_size >= need) {
        float2* part = (float2*)d_ws;
        dim3 g1(P1, NB), g2(625, NB), blk(256);
        k_part<<<g1, blk, 0, stream>>>(anchors, gts, part);
        k_assign2<<<g2, blk, 0, stream>>>(anchors, gts, scores, confs, part,
                                          labels_out, boxes_out);
    } else {
        float* highest = (float*)d_ws;
        hipMemsetAsync(d_ws, 0, (size_t)NB * NG * sizeof(float), stream);
        dim3 g1(1000, NB), g2(625, NB), blk(256);
        k_gt_highest_fb<<<g1, blk, 0, stream>>>(anchors, gts, highest);
        k_assign_fb<<<g2, blk, 0, stream>>>(anchors, gts, scores, confs, highest,
                                            labels_out, boxes_out);
    }
}

// Round 3
// 144.213 us; speedup vs baseline: 2.4421x; 1.0821x over previous
//
#include <hip/hip_runtime.h>

// Problem: B=4, A=160000 anchors, G=64 gt boxes.
// outputs (concat flat): labels [B,A] f32, matched_gt_boxes [B,A,4] f32
constexpr int NB = 4;
constexpr int NA = 160000;
constexpr int NG = 64;

// Two-dispatch scheme: k_part (1024-thread blocks, 16 waves x 40 anchors,
// the proven round-0 inner-loop shape + cross-wave LDS reduce -> 1 partial
// per 640 anchors); k_assign2 (4 anchors/thread) reduces the 250 partials
// in its prologue then does the per-anchor match.
constexpr int P1   = 250;         // partial slots per (b,g) -> ws = 512000 B
constexpr int APB1 = NA / P1;     // 640 anchors per k_part block
constexpr int APW  = 40;          // anchors per wave (16 waves * 40 = 640)
constexpr int AB2  = 1024;        // anchors per k_assign2 block (4/thread)
constexpr int GX2  = (NA + AB2 - 1) / AB2;   // 157 blocks per batch

// --- exact-rounding helpers -------------------------------------------------
// contract(off): stop fma fusion that would change rounding vs numpy.
__device__ __forceinline__ float box_area(float x0, float y0, float x1, float y1) {
#pragma clang fp contract(off)
    return (x1 - x0) * (y1 - y0);
}

// inter/denom with the exact op order of the numpy reference; shared by both
// kernels so phase-1's deferred quotient is bit-identical to phase-2's.
__device__ __forceinline__ void inter_denom(float gx0, float gy0, float gx1, float gy1, float garea,
                                            float ax0, float ay0, float ax1, float ay1, float aarea,
                                            float& inter, float& denom) {
#pragma clang fp contract(off)
    float ltx = fmaxf(gx0, ax0);
    float lty = fmaxf(gy0, ay0);
    float rbx = fminf(gx1, ax1);
    float rby = fminf(gy1, ay1);
    float w = fmaxf(rbx - ltx, 0.0f);
    float h = fmaxf(rby - lty, 0.0f);
    inter = w * h;
    float s = garea + aarea;        // numpy: area_gt + area_anchor
    denom = s - inter;
}

// exact comparison  i1/d1 > i2/d2  (all >= 0, d > 0), pure f32:
// FMA two-product gives the EXACT products p+e; ordering decided on the
// rounded products, ties broken on the exact tails (real-number ordering).
// Harness-validated bit-exact (absmax = 0.0, rounds 1-2).
__device__ __forceinline__ bool frac_gt(float i1, float d1, float i2, float d2) {
#pragma clang fp contract(off)
    float p1 = i1 * d2;
    float p2 = i2 * d1;
    float e1 = fmaf(i1, d2, -p1);
    float e2 = fmaf(i2, d1, -p2);
    return (p1 > p2) || ((p1 == p2) && (e1 > e2));
}

// Correctly-rounded f32 divide for our operand range (d in [16, ~5.7e4],
// n in [0, ~1.6e4]): the numerical core LLVM emits for `/` (rcp + NR + 2
// exact-residual FMA corrections) minus div_scale/div_fmas/div_fixup —
// bit-identical results (harness-validated rounds 1-2), and NO implicit VCC
// dependency, so independent chains pipeline freely.
__device__ __forceinline__ float div_rn(float n, float d) {
    float y = __builtin_amdgcn_rcpf(d);
    float e = fmaf(-d, y, 1.0f);
    y = fmaf(e, y, y);
    float q = n * y;
    float r = fmaf(-d, q, n);
    q = fmaf(r, y, q);
    float r2 = fmaf(-d, q, n);
    return fmaf(r2, y, q);
}

// --- kernel 1: per-block per-gt best (inter,denom) partials -----------------
// grid (P1, NB), block 1024 = 16 waves. Wave w scans 40 CONTIGUOUS anchors
// [j*640 + w*40, +40) with wave-uniform s_load addresses, unroll 8 — the
// round-0 machine shape (16000 waves total = 15.6/SIMD for latency hiding).
__global__ __launch_bounds__(1024) void k_part(
        const float* __restrict__ anchors, const float* __restrict__ gts,
        float2* __restrict__ part /* [NB][P1][NG] */) {
    const int b = blockIdx.y;
    const int j = blockIdx.x;
    const int lane = threadIdx.x & 63;
    const int wid = __builtin_amdgcn_readfirstlane(threadIdx.x >> 6);

    const float4* __restrict__ anc =
        reinterpret_cast<const float4*>(anchors) + (size_t)b * NA;
    float4 g = reinterpret_cast<const float4*>(gts)[b * NG + lane];
    float garea = box_area(g.x, g.y, g.z, g.w);

    const int base = j * APB1 + wid * APW;
    float bi = 0.0f, bd = 1.0f;                     // best (inter,denom): q=0
#pragma unroll 8
    for (int i = 0; i < APW; ++i) {
        float4 a = anc[base + i];                   // wave-uniform -> s_load
        float aarea = box_area(a.x, a.y, a.z, a.w);
        float inter, denom;
        inter_denom(g.x, g.y, g.z, g.w, garea, a.x, a.y, a.z, a.w, aarea,
                    inter, denom);
        if (frac_gt(inter, denom, bi, bd)) { bi = inter; bd = denom; }
    }

    __shared__ float pi[16][NG], pd[16][NG];
    pi[wid][lane] = bi;
    pd[wid][lane] = bd;
    __syncthreads();
    if (threadIdx.x < NG) {
        float ci = pi[0][threadIdx.x], cd = pd[0][threadIdx.x];
#pragma unroll
        for (int wv = 1; wv < 16; ++wv) {
            float ni = pi[wv][threadIdx.x], nd = pd[wv][threadIdx.x];
            if (frac_gt(ni, nd, ci, cd)) { ci = ni; cd = nd; }
        }
        // coalesced 64 x 8B store; layout [p][g] so k2's reduce is coalesced
        part[((size_t)b * P1 + j) * NG + threadIdx.x] = make_float2(ci, cd);
    }
}

// --- kernel 2: reduce partials + per-anchor match + labels ------------------
// grid (GX2, NB), block 256, FOUR anchors per thread (ai = bx*1024 + t + k*256)
// -> one ds_read pair per gt feeds 4 independent IoU+div chains (4x LDS
// amortization, 4x ILP); only 628 blocks redo the 250-partial reduce.
__global__ __launch_bounds__(256) void k_assign2(
        const float* __restrict__ anchors, const float* __restrict__ gts,
        const float* __restrict__ scores, const int* __restrict__ confs,
        const float2* __restrict__ part,
        float* __restrict__ labels_out, float4* __restrict__ boxes_out) {
    __shared__ float4 sg[NG];       // gt box
    __shared__ float2 sah[NG];      // {garea, highest}
    __shared__ float  ssc[NG];
    __shared__ int    scf[NG];
    __shared__ float  rpi[4][NG], rpd[4][NG];

    const int b = blockIdx.y;
    if (threadIdx.x < NG) {
        const int gi = threadIdx.x;
        sg[gi]  = reinterpret_cast<const float4*>(gts)[b * NG + gi];
        ssc[gi] = scores[b * NG + gi];
        scf[gi] = confs[b * NG + gi];
    }

    {   // partial reduce: 256 threads, ~63 coalesced L2-hit loads each
        const int gi = threadIdx.x & 63;
        const int c  = threadIdx.x >> 6;
        float ci = 0.0f, cd = 1.0f;
#pragma unroll 4
        for (int p = c; p < P1; p += 4) {
            float2 v = part[((size_t)b * P1 + p) * NG + gi];
            if (frac_gt(v.x, v.y, ci, cd)) { ci = v.x; cd = v.y; }
        }
        rpi[c][gi] = ci;
        rpd[c][gi] = cd;
    }
    __syncthreads();
    if (threadIdx.x < NG) {
        const int gi = threadIdx.x;
        float ci = rpi[0][gi], cd = rpd[0][gi];
#pragma unroll
        for (int wv = 1; wv < 4; ++wv) {
            float ni = rpi[wv][gi], nd = rpd[wv][gi];
            if (frac_gt(ni, nd, ci, cd)) { ci = ni; cd = nd; }
        }
        float4 gv = sg[gi];                         // written by this thread
        sah[gi] = make_float2(box_area(gv.x, gv.y, gv.z, gv.w),
                              div_rn(ci, cd));      // single rounded quotient
    }
    __syncthreads();

    const int base2 = blockIdx.x * AB2;
    const float4* __restrict__ anc =
        reinterpret_cast<const float4*>(anchors) + (size_t)b * NA;

    float4 av[4];
    float  aarea[4];
    float  best[4]    = {-1.0f, -1.0f, -1.0f, -1.0f};
    int    matches[4] = {0, 0, 0, 0};
    bool   lowq[4]    = {false, false, false, false};
#pragma unroll
    for (int k = 0; k < 4; ++k) {
        int ai = base2 + threadIdx.x + k * 256;
        int ac = ai < NA ? ai : NA - 1;             // clamp: compute is valid,
        av[k] = anc[ac];                            // store is guarded below
        aarea[k] = box_area(av[k].x, av[k].y, av[k].z, av[k].w);
    }

#pragma unroll 2
    for (int g = 0; g < NG; ++g) {
        float4 gb = sg[g];                          // ds_read_b128 broadcast
        float2 ah = sah[g];                         // ds_read_b64 broadcast
#pragma unroll
        for (int k = 0; k < 4; ++k) {
            float inter, denom;
            inter_denom(gb.x, gb.y, gb.z, gb.w, ah.x,
                        av[k].x, av[k].y, av[k].z, av[k].w, aarea[k],
                        inter, denom);
            float v = div_rn(inter, denom);         // no VCC: 4 chains overlap
            if (v > best[k]) { best[k] = v; matches[k] = g; }  // FIRST max
            lowq[k] |= (v == ah.y);                 // bit-exact equality
        }
    }

#pragma unroll
    for (int k = 0; k < 4; ++k) {
        int ai = base2 + threadIdx.x + k * 256;
        if (ai >= NA) continue;

        int m    = (best[k] < 0.3f) ? -1 : ((best[k] < 0.7f) ? -2 : matches[k]);
        int midx = lowq[k] ? matches[k] : m;
        int cl   = (midx < 0) ? 0 : midx;

        float4 mg = sg[cl];
        float  sc = ssc[cl];
        int    cf = scf[cl];

        bool pos = (midx >= 0);
        float lab = pos ? 1.0f : 0.0f;
        lab = fminf(lab, sc);
        if (midx == -1) lab = 0.0f;
        if (midx == -2) lab = -1.0f;
        if (sc < 1.0f && pos) lab = -1.0f;
        if (cf == 0 && pos) lab = -1.0f;

        labels_out[(size_t)b * NA + ai] = lab;
        boxes_out[(size_t)b * NA + ai] = mg;
    }
}

// --- fallback: round-0 3-dispatch path (if ws is too small for partials) ----
__global__ __launch_bounds__(256) void k_gt_highest_fb(
        const float* __restrict__ anchors, const float* __restrict__ gts,
        float* __restrict__ highest /* [B*G], pre-zeroed */) {
    const int b = blockIdx.y;
    const int lane = threadIdx.x & 63;
    const int wid = __builtin_amdgcn_readfirstlane(threadIdx.x >> 6);

    const float4* __restrict__ anc =
        reinterpret_cast<const float4*>(anchors) + (size_t)b * NA;
    float4 g = reinterpret_cast<const float4*>(gts)[b * NG + lane];
    float garea = box_area(g.x, g.y, g.z, g.w);

    const int base = blockIdx.x * 160 + wid * 40;
    float bi = 0.0f, bd = 1.0f;
#pragma unroll 8
    for (int i = 0; i < 40; ++i) {
        float4 a = anc[base + i];
        float aarea = box_area(a.x, a.y, a.z, a.w);
        float inter, denom;
        inter_denom(g.x, g.y, g.z, g.w, garea, a.x, a.y, a.z, a.w, aarea,
                    inter, denom);
        if (frac_gt(inter, denom, bi, bd)) { bi = inter; bd = denom; }
    }

    __shared__ float pi[4][NG], pd[4][NG];
    pi[wid][lane] = bi;
    pd[wid][lane] = bd;
    __syncthreads();
    if (threadIdx.x < NG) {
        float ci = pi[0][threadIdx.x], cd = pd[0][threadIdx.x];
#pragma unroll
        for (int wv = 1; wv < 4; ++wv) {
            float ni = pi[wv][threadIdx.x], nd = pd[wv][threadIdx.x];
            if (frac_gt(ni, nd, ci, cd)) { ci = ni; cd = nd; }
        }
        atomicMax(reinterpret_cast<int*>(&highest[b * NG + threadIdx.x]),
                  __float_as_int(div_rn(ci, cd)));
    }
}

__global__ __launch_bounds__(256) void k_assign_fb(
        const float* __restrict__ anchors, const float* __restrict__ gts,
        const float* __restrict__ scores, const int* __restrict__ confs,
        const float* __restrict__ highest,
        float* __restrict__ labels_out, float4* __restrict__ boxes_out) {
    __shared__ float4 sg[NG];
    __shared__ float2 sah[NG];
    __shared__ float  ssc[NG];
    __shared__ int    scf[NG];

    const int b = blockIdx.y;
    if (threadIdx.x < NG) {
        const int gi = threadIdx.x;
        float4 gv = reinterpret_cast<const float4*>(gts)[b * NG + gi];
        sg[gi] = gv;
        sah[gi] = make_float2(box_area(gv.x, gv.y, gv.z, gv.w),
                              highest[b * NG + gi]);
        ssc[gi] = scores[b * NG + gi];
        scf[gi] = confs[b * NG + gi];
    }
    __syncthreads();

    const int ai = blockIdx.x * 256 + threadIdx.x;
    const float4* __restrict__ anc =
        reinterpret_cast<const float4*>(anchors) + (size_t)b * NA;
    float4 av = anc[ai];
    float aarea = box_area(av.x, av.y, av.z, av.w);

    float best = -1.0f;
    int   matches = 0;
    bool  lowq = false;
#pragma unroll 4
    for (int g = 0; g < NG; ++g) {
        float4 gb = sg[g];
        float2 ah = sah[g];
        float inter, denom;
        inter_denom(gb.x, gb.y, gb.z, gb.w, ah.x,
                    av.x, av.y, av.z, av.w, aarea, inter, denom);
        float v = div_rn(inter, denom);
        if (v > best) { best = v; matches = g; }
        lowq |= (v == ah.y);
    }

    int m    = (best < 0.3f) ? -1 : ((best < 0.7f) ? -2 : matches);
    int midx = lowq ? matches : m;
    int cl   = (midx < 0) ? 0 : midx;

    float4 mg = sg[cl];
    float  sc = ssc[cl];
    int    cf = scf[cl];

    bool pos = (midx >= 0);
    float lab = pos ? 1.0f : 0.0f;
    lab = fminf(lab, sc);
    if (midx == -1) lab = 0.0f;
    if (midx == -2) lab = -1.0f;
    if (sc < 1.0f && pos) lab = -1.0f;
    if (cf == 0 && pos) lab = -1.0f;

    labels_out[(size_t)b * NA + ai] = lab;
    boxes_out[(size_t)b * NA + ai] = mg;
}

extern "C" void kernel_launch(void* const* d_in, const int* in_sizes, int n_in,
                              void* d_out, int out_size, void* d_ws, size_t ws_size,
                              hipStream_t stream) {
    const float* anchors = (const float*)d_in[0];   // [B,A,4]
    const float* gts     = (const float*)d_in[1];   // [B,G,4]
    const float* scores  = (const float*)d_in[2];   // [B,G]
    const int*   confs   = (const int*)d_in[3];     // [B,G]

    float* labels_out = (float*)d_out;                              // [B,A]
    float4* boxes_out = (float4*)((float*)d_out + (size_t)NB * NA); // [B,A,4]

    const size_t need = (size_t)NB * P1 * NG * sizeof(float2);      // 512 KB
    if (ws_size >= need) {
        float2* part = (float2*)d_ws;
        dim3 g1(P1, NB), g2(GX2, NB);
        k_part<<<g1, dim3(1024), 0, stream>>>(anchors, gts, part);
        k_assign2<<<g2, dim3(256), 0, stream>>>(anchors, gts, scores, confs,
                                                part, labels_out, boxes_out);
    } else {
        float* highest = (float*)d_ws;
        hipMemsetAsync(d_ws, 0, (size_t)NB * NG * sizeof(float), stream);
        dim3 g1(1000, NB), g2(625, NB), blk(256);
        k_gt_highest_fb<<<g1, blk, 0, stream>>>(anchors, gts, highest);
        k_assign_fb<<<g2, blk, 0, stream>>>(anchors, gts, scores, confs,
                                            highest, labels_out, boxes_out);
    }
}

// Round 4
// 137.385 us; speedup vs baseline: 2.5634x; 1.0497x over previous
//
#include <hip/hip_runtime.h>

// Problem: B=4, A=160000 anchors, G=64 gt boxes.
// outputs (concat flat): labels [B,A] f32, matched_gt_boxes [B,A,4] f32
constexpr int NB = 4;
constexpr int NA = 160000;
constexpr int NG = 64;

// Two-dispatch scheme:
//  k_part   : 1024-thread blocks, anchors LDS-staged (coalesced burst), 16
//             waves x 40 anchors via broadcast ds_read; cross-wave reduce ->
//             one (inter,denom) partial per gt per 640 anchors.
//  k_assign2: 2 anchors/thread, reduces the 250 partials in its prologue,
//             then per-anchor match with 8 independent divide chains.
constexpr int P1   = 250;         // partial slots per (b,g) -> ws = 512000 B
constexpr int APB1 = NA / P1;     // 640 anchors per k_part block
constexpr int APW  = 40;          // anchors per wave (16 waves * 40 = 640)
constexpr int AB2  = 512;         // anchors per k_assign2 block (2/thread)
constexpr int GX2  = (NA + AB2 - 1) / AB2;   // 313 blocks per batch

// --- exact-rounding helpers -------------------------------------------------
// contract(off): stop fma fusion that would change rounding vs numpy.
__device__ __forceinline__ float box_area(float x0, float y0, float x1, float y1) {
#pragma clang fp contract(off)
    return (x1 - x0) * (y1 - y0);
}

// inter/denom with the exact op order of the numpy reference; shared by both
// kernels so phase-1's deferred quotient is bit-identical to phase-2's.
__device__ __forceinline__ void inter_denom(float gx0, float gy0, float gx1, float gy1, float garea,
                                            float ax0, float ay0, float ax1, float ay1, float aarea,
                                            float& inter, float& denom) {
#pragma clang fp contract(off)
    float ltx = fmaxf(gx0, ax0);
    float lty = fmaxf(gy0, ay0);
    float rbx = fminf(gx1, ax1);
    float rby = fminf(gy1, ay1);
    float w = fmaxf(rbx - ltx, 0.0f);
    float h = fmaxf(rby - lty, 0.0f);
    inter = w * h;
    float s = garea + aarea;        // numpy: area_gt + area_anchor
    denom = s - inter;
}

// exact comparison  i1/d1 > i2/d2  (all >= 0, d > 0), pure f32:
// FMA two-product gives the EXACT products p+e; ordering decided on the
// rounded products, ties broken on the exact tails (real-number ordering).
// The tie-break is REQUIRED: two near-equal fractions can straddle a quotient
// rounding boundary even when their rounded cross-products tie.
// Harness-validated bit-exact (absmax = 0.0, rounds 1-3).
__device__ __forceinline__ bool frac_gt(float i1, float d1, float i2, float d2) {
#pragma clang fp contract(off)
    float p1 = i1 * d2;
    float p2 = i2 * d1;
    float e1 = fmaf(i1, d2, -p1);
    float e2 = fmaf(i2, d1, -p2);
    return (p1 > p2) || ((p1 == p2) && (e1 > e2));
}

// Correctly-rounded f32 divide for our operand range (d in [16, ~5.7e4],
// n in [0, ~1.6e4]): the numerical core LLVM emits for `/` (rcp + NR + 2
// exact-residual FMA corrections) minus div_scale/div_fmas/div_fixup —
// bit-identical results (harness-validated rounds 1-3), and NO implicit VCC
// dependency, so independent chains pipeline freely.
__device__ __forceinline__ float div_rn(float n, float d) {
    float y = __builtin_amdgcn_rcpf(d);
    float e = fmaf(-d, y, 1.0f);
    y = fmaf(e, y, y);
    float q = n * y;
    float r = fmaf(-d, q, n);
    q = fmaf(r, y, q);
    float r2 = fmaf(-d, q, n);
    return fmaf(r2, y, q);
}

// --- kernel 1: per-block per-gt best (inter,denom) partials -----------------
// grid (P1, NB), block 1024 = 16 waves. Coalesced stage of the block's 640
// anchors into LDS (one vector-load burst), then wave w scans its 40 anchors
// via uniform-address ds_read_b128 (broadcast, conflict-free) — replaces the
// round-0 streaming s_load K$-miss chain. 18 KB LDS -> 2 blocks/CU = 32
// waves/CU (100% occupancy vs ~50% before).
__global__ __launch_bounds__(1024, 2) void k_part(
        const float* __restrict__ anchors, const float* __restrict__ gts,
        float2* __restrict__ part /* [NB][P1][NG] */) {
    __shared__ float4 sa[APB1];                     // 640 anchors, 10 KB
    __shared__ float pi[16][NG], pd[16][NG];        // 8 KB

    const int b = blockIdx.y;
    const int j = blockIdx.x;
    const int lane = threadIdx.x & 63;
    const int wid = __builtin_amdgcn_readfirstlane(threadIdx.x >> 6);

    const float4* __restrict__ anc =
        reinterpret_cast<const float4*>(anchors) + (size_t)b * NA;
    if (threadIdx.x < APB1)
        sa[threadIdx.x] = anc[j * APB1 + threadIdx.x];  // coalesced burst

    float4 g = reinterpret_cast<const float4*>(gts)[b * NG + lane];
    float garea = box_area(g.x, g.y, g.z, g.w);
    __syncthreads();

    float bi = 0.0f, bd = 1.0f;                     // best (inter,denom): q=0
#pragma unroll 8
    for (int i = 0; i < APW; ++i) {
        float4 a = sa[wid * APW + i];               // uniform addr -> broadcast
        float aarea = box_area(a.x, a.y, a.z, a.w);
        float inter, denom;
        inter_denom(g.x, g.y, g.z, g.w, garea, a.x, a.y, a.z, a.w, aarea,
                    inter, denom);
        if (frac_gt(inter, denom, bi, bd)) { bi = inter; bd = denom; }
    }

    pi[wid][lane] = bi;
    pd[wid][lane] = bd;
    __syncthreads();
    if (threadIdx.x < NG) {
        float ci = pi[0][threadIdx.x], cd = pd[0][threadIdx.x];
#pragma unroll
        for (int wv = 1; wv < 16; ++wv) {
            float ni = pi[wv][threadIdx.x], nd = pd[wv][threadIdx.x];
            if (frac_gt(ni, nd, ci, cd)) { ci = ni; cd = nd; }
        }
        // coalesced 64 x 8B store; layout [p][g] so k2's reduce is coalesced
        part[((size_t)b * P1 + j) * NG + threadIdx.x] = make_float2(ci, cd);
    }
}

// --- kernel 2: reduce partials + per-anchor match + labels ------------------
// grid (GX2, NB), block 256, TWO anchors per thread (ai = bx*512 + t + k*256).
// launch_bounds(256,2) lets the allocator keep 2 chains x unroll-4 gt loop
// (8 independent IoU+div chains) fully in registers; 1252 blocks = 4.9
// waves/SIMD of TLP on top.
__global__ __launch_bounds__(256, 2) void k_assign2(
        const float* __restrict__ anchors, const float* __restrict__ gts,
        const float* __restrict__ scores, const int* __restrict__ confs,
        const float2* __restrict__ part,
        float* __restrict__ labels_out, float4* __restrict__ boxes_out) {
    __shared__ float4 sg[NG];       // gt box
    __shared__ float2 sah[NG];      // {garea, highest}
    __shared__ float  ssc[NG];
    __shared__ int    scf[NG];
    __shared__ float  rpi[4][NG], rpd[4][NG];

    const int b = blockIdx.y;
    if (threadIdx.x < NG) {
        const int gi = threadIdx.x;
        sg[gi]  = reinterpret_cast<const float4*>(gts)[b * NG + gi];
        ssc[gi] = scores[b * NG + gi];
        scf[gi] = confs[b * NG + gi];
    }

    {   // partial reduce: 256 threads, ~63 coalesced L2/L3-hit loads each
        const int gi = threadIdx.x & 63;
        const int c  = threadIdx.x >> 6;
        float ci = 0.0f, cd = 1.0f;
#pragma unroll 8
        for (int p = c; p < P1; p += 4) {
            float2 v = part[((size_t)b * P1 + p) * NG + gi];
            if (frac_gt(v.x, v.y, ci, cd)) { ci = v.x; cd = v.y; }
        }
        rpi[c][gi] = ci;
        rpd[c][gi] = cd;
    }
    __syncthreads();
    if (threadIdx.x < NG) {
        const int gi = threadIdx.x;
        float ci = rpi[0][gi], cd = rpd[0][gi];
#pragma unroll
        for (int wv = 1; wv < 4; ++wv) {
            float ni = rpi[wv][gi], nd = rpd[wv][gi];
            if (frac_gt(ni, nd, ci, cd)) { ci = ni; cd = nd; }
        }
        float4 gv = sg[gi];                         // written by this thread
        sah[gi] = make_float2(box_area(gv.x, gv.y, gv.z, gv.w),
                              div_rn(ci, cd));      // single rounded quotient
    }
    __syncthreads();

    const int base2 = blockIdx.x * AB2;
    const float4* __restrict__ anc =
        reinterpret_cast<const float4*>(anchors) + (size_t)b * NA;

    float4 av[2];
    float  aarea[2];
    float  best[2]    = {-1.0f, -1.0f};
    int    matches[2] = {0, 0};
    bool   lowq[2]    = {false, false};
#pragma unroll
    for (int k = 0; k < 2; ++k) {
        int ai = base2 + threadIdx.x + k * 256;
        int ac = ai < NA ? ai : NA - 1;             // clamp: compute is valid,
        av[k] = anc[ac];                            // store is guarded below
        aarea[k] = box_area(av[k].x, av[k].y, av[k].z, av[k].w);
    }

#pragma unroll 4
    for (int g = 0; g < NG; ++g) {
        float4 gb = sg[g];                          // ds_read_b128 broadcast
        float2 ah = sah[g];                         // ds_read_b64 broadcast
#pragma unroll
        for (int k = 0; k < 2; ++k) {
            float inter, denom;
            inter_denom(gb.x, gb.y, gb.z, gb.w, ah.x,
                        av[k].x, av[k].y, av[k].z, av[k].w, aarea[k],
                        inter, denom);
            float v = div_rn(inter, denom);         // no VCC: chains overlap
            if (v > best[k]) { best[k] = v; matches[k] = g; }  // FIRST max
            lowq[k] |= (v == ah.y);                 // bit-exact equality
        }
    }

#pragma unroll
    for (int k = 0; k < 2; ++k) {
        int ai = base2 + threadIdx.x + k * 256;
        if (ai >= NA) continue;

        int m    = (best[k] < 0.3f) ? -1 : ((best[k] < 0.7f) ? -2 : matches[k]);
        int midx = lowq[k] ? matches[k] : m;
        int cl   = (midx < 0) ? 0 : midx;

        float4 mg = sg[cl];
        float  sc = ssc[cl];
        int    cf = scf[cl];

        bool pos = (midx >= 0);
        float lab = pos ? 1.0f : 0.0f;
        lab = fminf(lab, sc);
        if (midx == -1) lab = 0.0f;
        if (midx == -2) lab = -1.0f;
        if (sc < 1.0f && pos) lab = -1.0f;
        if (cf == 0 && pos) lab = -1.0f;

        labels_out[(size_t)b * NA + ai] = lab;
        boxes_out[(size_t)b * NA + ai] = mg;
    }
}

// --- fallback: round-0 3-dispatch path (if ws is too small for partials) ----
__global__ __launch_bounds__(256) void k_gt_highest_fb(
        const float* __restrict__ anchors, const float* __restrict__ gts,
        float* __restrict__ highest /* [B*G], pre-zeroed */) {
    const int b = blockIdx.y;
    const int lane = threadIdx.x & 63;
    const int wid = __builtin_amdgcn_readfirstlane(threadIdx.x >> 6);

    const float4* __restrict__ anc =
        reinterpret_cast<const float4*>(anchors) + (size_t)b * NA;
    float4 g = reinterpret_cast<const float4*>(gts)[b * NG + lane];
    float garea = box_area(g.x, g.y, g.z, g.w);

    const int base = blockIdx.x * 160 + wid * 40;
    float bi = 0.0f, bd = 1.0f;
#pragma unroll 8
    for (int i = 0; i < 40; ++i) {
        float4 a = anc[base + i];
        float aarea = box_area(a.x, a.y, a.z, a.w);
        float inter, denom;
        inter_denom(g.x, g.y, g.z, g.w, garea, a.x, a.y, a.z, a.w, aarea,
                    inter, denom);
        if (frac_gt(inter, denom, bi, bd)) { bi = inter; bd = denom; }
    }

    __shared__ float pi[4][NG], pd[4][NG];
    pi[wid][lane] = bi;
    pd[wid][lane] = bd;
    __syncthreads();
    if (threadIdx.x < NG) {
        float ci = pi[0][threadIdx.x], cd = pd[0][threadIdx.x];
#pragma unroll
        for (int wv = 1; wv < 4; ++wv) {
            float ni = pi[wv][threadIdx.x], nd = pd[wv][threadIdx.x];
            if (frac_gt(ni, nd, ci, cd)) { ci = ni; cd = nd; }
        }
        atomicMax(reinterpret_cast<int*>(&highest[b * NG + threadIdx.x]),
                  __float_as_int(div_rn(ci, cd)));
    }
}

__global__ __launch_bounds__(256) void k_assign_fb(
        const float* __restrict__ anchors, const float* __restrict__ gts,
        const float* __restrict__ scores, const int* __restrict__ confs,
        const float* __restrict__ highest,
        float* __restrict__ labels_out, float4* __restrict__ boxes_out) {
    __shared__ float4 sg[NG];
    __shared__ float2 sah[NG];
    __shared__ float  ssc[NG];
    __shared__ int    scf[NG];

    const int b = blockIdx.y;
    if (threadIdx.x < NG) {
        const int gi = threadIdx.x;
        float4 gv = reinterpret_cast<const float4*>(gts)[b * NG + gi];
        sg[gi] = gv;
        sah[gi] = make_float2(box_area(gv.x, gv.y, gv.z, gv.w),
                              highest[b * NG + gi]);
        ssc[gi] = scores[b * NG + gi];
        scf[gi] = confs[b * NG + gi];
    }
    __syncthreads();

    const int ai = blockIdx.x * 256 + threadIdx.x;
    const float4* __restrict__ anc =
        reinterpret_cast<const float4*>(anchors) + (size_t)b * NA;
    float4 av = anc[ai];
    float aarea = box_area(av.x, av.y, av.z, av.w);

    float best = -1.0f;
    int   matches = 0;
    bool  lowq = false;
#pragma unroll 4
    for (int g = 0; g < NG; ++g) {
        float4 gb = sg[g];
        float2 ah = sah[g];
        float inter, denom;
        inter_denom(gb.x, gb.y, gb.z, gb.w, ah.x,
                    av.x, av.y, av.z, av.w, aarea, inter, denom);
        float v = div_rn(inter, denom);
        if (v > best) { best = v; matches = g; }
        lowq |= (v == ah.y);
    }

    int m    = (best < 0.3f) ? -1 : ((best < 0.7f) ? -2 : matches);
    int midx = lowq ? matches : m;
    int cl   = (midx < 0) ? 0 : midx;

    float4 mg = sg[cl];
    float  sc = ssc[cl];
    int    cf = scf[cl];

    bool pos = (midx >= 0);
    float lab = pos ? 1.0f : 0.0f;
    lab = fminf(lab, sc);
    if (midx == -1) lab = 0.0f;
    if (midx == -2) lab = -1.0f;
    if (sc < 1.0f && pos) lab = -1.0f;
    if (cf == 0 && pos) lab = -1.0f;

    labels_out[(size_t)b * NA + ai] = lab;
    boxes_out[(size_t)b * NA + ai] = mg;
}

extern "C" void kernel_launch(void* const* d_in, const int* in_sizes, int n_in,
                              void* d_out, int out_size, void* d_ws, size_t ws_size,
                              hipStream_t stream) {
    const float* anchors = (const float*)d_in[0];   // [B,A,4]
    const float* gts     = (const float*)d_in[1];   // [B,G,4]
    const float* scores  = (const float*)d_in[2];   // [B,G]
    const int*   confs   = (const int*)d_in[3];     // [B,G]

    float* labels_out = (float*)d_out;                              // [B,A]
    float4* boxes_out = (float4*)((float*)d_out + (size_t)NB * NA); // [B,A,4]

    const size_t need = (size_t)NB * P1 * NG * sizeof(float2);      // 512 KB
    if (ws_size >= need) {
        float2* part = (float2*)d_ws;
        dim3 g1(P1, NB), g2(GX2, NB);
        k_part<<<g1, dim3(1024), 0, stream>>>(anchors, gts, part);
        k_assign2<<<g2, dim3(256), 0, stream>>>(anchors, gts, scores, confs,
                                                part, labels_out, boxes_out);
    } else {
        float* highest = (float*)d_ws;
        hipMemsetAsync(d_ws, 0, (size_t)NB * NG * sizeof(float), stream);
        dim3 g1(1000, NB), g2(625, NB), blk(256);
        k_gt_highest_fb<<<g1, blk, 0, stream>>>(anchors, gts, highest);
        k_assign_fb<<<g2, blk, 0, stream>>>(anchors, gts, scores, confs,
                                            highest, labels_out, boxes_out);
    }
}

// Round 5
// 133.080 us; speedup vs baseline: 2.6464x; 1.0323x over previous
//
#include <hip/hip_runtime.h>

// Problem: B=4, A=160000 anchors, G=64 gt boxes.
// outputs (concat flat): labels [B,A] f32, matched_gt_boxes [B,A,4] f32
constexpr int NB = 4;
constexpr int NA = 160000;
constexpr int NG = 64;

// Two-dispatch scheme:
//  k_part   : 1024-thr blocks (2/CU), anchors LDS-staged, 16 waves x 40
//             anchors; per-block (inter,denom) partial per gt; the LAST
//             block per batch (module-global epoch counter, replay-safe)
//             reduces all 250 partials -> final highest[b][g].
//  k_assign2: 1 anchor/thread, 2500 blocks (9.8 waves/SIMD TLP), reads
//             highest directly (round-0 proven shape), div_rn main loop.
constexpr int P1   = 250;         // k_part blocks per batch
constexpr int APB1 = NA / P1;     // 640 anchors per k_part block
constexpr int APW  = 40;          // anchors per wave (16 waves * 40 = 640)

// Module-scope counter: zero-initialized at module load (guaranteed), then
// counted MODULO P1 -> "last block per batch" works for every graph replay
// without any memset dispatch.
__device__ int g_ctr[NB];

// --- exact-rounding helpers -------------------------------------------------
// contract(off): stop fma fusion that would change rounding vs numpy.
__device__ __forceinline__ float box_area(float x0, float y0, float x1, float y1) {
#pragma clang fp contract(off)
    return (x1 - x0) * (y1 - y0);
}

// inter/denom with the exact op order of the numpy reference; shared by both
// kernels so phase-1's deferred quotient is bit-identical to phase-2's.
__device__ __forceinline__ void inter_denom(float gx0, float gy0, float gx1, float gy1, float garea,
                                            float ax0, float ay0, float ax1, float ay1, float aarea,
                                            float& inter, float& denom) {
#pragma clang fp contract(off)
    float ltx = fmaxf(gx0, ax0);
    float lty = fmaxf(gy0, ay0);
    float rbx = fminf(gx1, ax1);
    float rby = fminf(gy1, ay1);
    float w = fmaxf(rbx - ltx, 0.0f);
    float h = fmaxf(rby - lty, 0.0f);
    inter = w * h;
    float s = garea + aarea;        // numpy: area_gt + area_anchor
    denom = s - inter;
}

// exact comparison  i1/d1 > i2/d2  (all >= 0, d > 0), pure f32:
// FMA two-product gives the EXACT products p+e; ordering decided on the
// rounded products, ties broken on the exact tails (real-number ordering).
// Harness-validated bit-exact (absmax = 0.0, rounds 1-4).
__device__ __forceinline__ bool frac_gt(float i1, float d1, float i2, float d2) {
#pragma clang fp contract(off)
    float p1 = i1 * d2;
    float p2 = i2 * d1;
    float e1 = fmaf(i1, d2, -p1);
    float e2 = fmaf(i2, d1, -p2);
    return (p1 > p2) || ((p1 == p2) && (e1 > e2));
}

// Correctly-rounded f32 divide for our operand range (d in [16, ~5.7e4],
// n in [0, ~1.6e4]): the numerical core LLVM emits for `/` (rcp + NR + 2
// exact-residual FMA corrections) minus div_scale/div_fmas/div_fixup —
// bit-identical results (harness-validated rounds 1-4), no VCC dependency.
__device__ __forceinline__ float div_rn(float n, float d) {
    float y = __builtin_amdgcn_rcpf(d);
    float e = fmaf(-d, y, 1.0f);
    y = fmaf(e, y, y);
    float q = n * y;
    float r = fmaf(-d, q, n);
    q = fmaf(r, y, q);
    float r2 = fmaf(-d, q, n);
    return fmaf(r2, y, q);
}

// pack/unpack float2 <-> u64 for agent-scope 8B atomics (symmetric, so the
// representation choice cancels out)
__device__ __forceinline__ unsigned long long pack2(float x, float y) {
    return (unsigned long long)__float_as_uint(x) |
           ((unsigned long long)__float_as_uint(y) << 32);
}
__device__ __forceinline__ void unpack2(unsigned long long u, float& x, float& y) {
    x = __uint_as_float((unsigned)(u & 0xffffffffu));
    y = __uint_as_float((unsigned)(u >> 32));
}

// --- kernel 1: per-gt max; last block per batch finalizes highest -----------
// grid (P1, NB), block 1024 = 16 waves, launch_bounds(1024,8) => 2 blocks/CU
// (32 waves/CU, 100% occupancy; VGPR capped at 64 — inner unroll 4 fits).
__global__ __launch_bounds__(1024, 8) void k_part(
        const float* __restrict__ anchors, const float* __restrict__ gts,
        float2* __restrict__ part /* [NB][P1][NG] */,
        float* __restrict__ highest /* [NB][NG] */) {
    __shared__ float4 sa[APB1];                     // 640 anchors, 10 KB
    __shared__ float pi[16][NG], pd[16][NG];        // 8 KB (reused by reducer)
    __shared__ int s_old;

    const int b = blockIdx.y;
    const int j = blockIdx.x;
    const int lane = threadIdx.x & 63;
    const int wid = __builtin_amdgcn_readfirstlane(threadIdx.x >> 6);

    const float4* __restrict__ anc =
        reinterpret_cast<const float4*>(anchors) + (size_t)b * NA;
    if (threadIdx.x < APB1)
        sa[threadIdx.x] = anc[j * APB1 + threadIdx.x];  // coalesced burst

    float4 g = reinterpret_cast<const float4*>(gts)[b * NG + lane];
    float garea = box_area(g.x, g.y, g.z, g.w);
    __syncthreads();

    float bi = 0.0f, bd = 1.0f;                     // best (inter,denom): q=0
#pragma unroll 4
    for (int i = 0; i < APW; ++i) {
        float4 a = sa[wid * APW + i];               // uniform addr -> broadcast
        float aarea = box_area(a.x, a.y, a.z, a.w);
        float inter, denom;
        inter_denom(g.x, g.y, g.z, g.w, garea, a.x, a.y, a.z, a.w, aarea,
                    inter, denom);
        if (frac_gt(inter, denom, bi, bd)) { bi = inter; bd = denom; }
    }

    pi[wid][lane] = bi;
    pd[wid][lane] = bd;
    __syncthreads();
    if (threadIdx.x < NG) {
        float ci = pi[0][threadIdx.x], cd = pd[0][threadIdx.x];
#pragma unroll
        for (int wv = 1; wv < 16; ++wv) {
            float ni = pi[wv][threadIdx.x], nd = pd[wv][threadIdx.x];
            if (frac_gt(ni, nd, ci, cd)) { ci = ni; cd = nd; }
        }
        // agent-scope publish: cross-XCD-coherent for the reducer block
        __hip_atomic_store(
            reinterpret_cast<unsigned long long*>(
                &part[((size_t)b * P1 + j) * NG + threadIdx.x]),
            pack2(ci, cd), __ATOMIC_RELAXED, __HIP_MEMORY_SCOPE_AGENT);
    }
    __syncthreads();                // drains the stores (waitcnt before barrier)
    if (threadIdx.x == 0) {
        __threadfence();            // device-scope release before the count
        s_old = atomicAdd(&g_ctr[b], 1);
    }
    __syncthreads();
    if ((s_old % P1) != P1 - 1) return;

    // ---- last block for batch b: reduce 250 partials -> highest[b][g] ------
    {
        const int gi = threadIdx.x & 63;
        const int c  = threadIdx.x >> 6;            // 16 chunks
        float ci = 0.0f, cd = 1.0f;
#pragma unroll 4
        for (int p = c; p < P1; p += 16) {
            unsigned long long u = __hip_atomic_load(
                reinterpret_cast<const unsigned long long*>(
                    &part[((size_t)b * P1 + p) * NG + gi]),
                __ATOMIC_RELAXED, __HIP_MEMORY_SCOPE_AGENT);
            float ni, nd;
            unpack2(u, ni, nd);
            if (frac_gt(ni, nd, ci, cd)) { ci = ni; cd = nd; }
        }
        pi[c][gi] = ci;
        pd[c][gi] = cd;
    }
    __syncthreads();
    if (threadIdx.x < NG) {
        float ci = pi[0][threadIdx.x], cd = pd[0][threadIdx.x];
#pragma unroll
        for (int wv = 1; wv < 16; ++wv) {
            float ni = pi[wv][threadIdx.x], nd = pd[wv][threadIdx.x];
            if (frac_gt(ni, nd, ci, cd)) { ci = ni; cd = nd; }
        }
        // plain store: inter-dispatch coherence covers k_assign2's reads
        highest[b * NG + threadIdx.x] = div_rn(ci, cd);
    }
}

// --- kernel 2: per-anchor match + labels (round-0 proven shape) -------------
// grid (625, NB), block 256, ONE anchor per thread; 2500 blocks = 9.8
// waves/SIMD of TLP; no partial-reduce prologue (reads final highest).
__global__ __launch_bounds__(256, 8) void k_assign2(
        const float* __restrict__ anchors, const float* __restrict__ gts,
        const float* __restrict__ scores, const int* __restrict__ confs,
        const float* __restrict__ highest,
        float* __restrict__ labels_out, float4* __restrict__ boxes_out) {
    __shared__ float4 sg[NG];       // gt box
    __shared__ float2 sah[NG];      // {garea, highest}
    __shared__ float  ssc[NG];
    __shared__ int    scf[NG];

    const int b = blockIdx.y;
    if (threadIdx.x < NG) {
        const int gi = threadIdx.x;
        float4 gv = reinterpret_cast<const float4*>(gts)[b * NG + gi];
        sg[gi]  = gv;
        sah[gi] = make_float2(box_area(gv.x, gv.y, gv.z, gv.w),
                              highest[b * NG + gi]);
        ssc[gi] = scores[b * NG + gi];
        scf[gi] = confs[b * NG + gi];
    }
    __syncthreads();

    const int ai = blockIdx.x * 256 + threadIdx.x;  // 0..159999 exactly
    const float4* __restrict__ anc =
        reinterpret_cast<const float4*>(anchors) + (size_t)b * NA;
    float4 av = anc[ai];
    float aarea = box_area(av.x, av.y, av.z, av.w);

    float best = -1.0f;             // all-zero row -> argmax 0 (first max)
    int   matches = 0;
    bool  lowq = false;
#pragma unroll 4
    for (int g = 0; g < NG; ++g) {
        float4 gb = sg[g];                          // ds_read_b128 broadcast
        float2 ah = sah[g];                         // ds_read_b64 broadcast
        float inter, denom;
        inter_denom(gb.x, gb.y, gb.z, gb.w, ah.x,
                    av.x, av.y, av.z, av.w, aarea, inter, denom);
        float v = div_rn(inter, denom);             // bit-exact IEEE quotient
        if (v > best) { best = v; matches = g; }    // strict > keeps FIRST max
        lowq |= (v == ah.y);                        // bit-exact equality
    }

    int m    = (best < 0.3f) ? -1 : ((best < 0.7f) ? -2 : matches);
    int midx = lowq ? matches : m;
    int cl   = (midx < 0) ? 0 : midx;

    float4 mg = sg[cl];
    float  sc = ssc[cl];
    int    cf = scf[cl];

    bool pos = (midx >= 0);
    float lab = pos ? 1.0f : 0.0f;
    lab = fminf(lab, sc);
    if (midx == -1) lab = 0.0f;
    if (midx == -2) lab = -1.0f;
    if (sc < 1.0f && pos) lab = -1.0f;
    if (cf == 0 && pos) lab = -1.0f;

    labels_out[(size_t)b * NA + ai] = lab;
    boxes_out[(size_t)b * NA + ai] = mg;
}

// --- fallback (ws too small): memset + atomicMax highest + k_assign2 --------
__global__ __launch_bounds__(256) void k_gt_highest_fb(
        const float* __restrict__ anchors, const float* __restrict__ gts,
        float* __restrict__ highest /* [B*G], pre-zeroed */) {
    const int b = blockIdx.y;
    const int lane = threadIdx.x & 63;
    const int wid = __builtin_amdgcn_readfirstlane(threadIdx.x >> 6);

    const float4* __restrict__ anc =
        reinterpret_cast<const float4*>(anchors) + (size_t)b * NA;
    float4 g = reinterpret_cast<const float4*>(gts)[b * NG + lane];
    float garea = box_area(g.x, g.y, g.z, g.w);

    const int base = blockIdx.x * 160 + wid * 40;
    float bi = 0.0f, bd = 1.0f;
#pragma unroll 8
    for (int i = 0; i < 40; ++i) {
        float4 a = anc[base + i];
        float aarea = box_area(a.x, a.y, a.z, a.w);
        float inter, denom;
        inter_denom(g.x, g.y, g.z, g.w, garea, a.x, a.y, a.z, a.w, aarea,
                    inter, denom);
        if (frac_gt(inter, denom, bi, bd)) { bi = inter; bd = denom; }
    }

    __shared__ float pi[4][NG], pd[4][NG];
    pi[wid][lane] = bi;
    pd[wid][lane] = bd;
    __syncthreads();
    if (threadIdx.x < NG) {
        float ci = pi[0][threadIdx.x], cd = pd[0][threadIdx.x];
#pragma unroll
        for (int wv = 1; wv < 4; ++wv) {
            float ni = pi[wv][threadIdx.x], nd = pd[wv][threadIdx.x];
            if (frac_gt(ni, nd, ci, cd)) { ci = ni; cd = nd; }
        }
        atomicMax(reinterpret_cast<int*>(&highest[b * NG + threadIdx.x]),
                  __float_as_int(div_rn(ci, cd)));
    }
}

extern "C" void kernel_launch(void* const* d_in, const int* in_sizes, int n_in,
                              void* d_out, int out_size, void* d_ws, size_t ws_size,
                              hipStream_t stream) {
    const float* anchors = (const float*)d_in[0];   // [B,A,4]
    const float* gts     = (const float*)d_in[1];   // [B,G,4]
    const float* scores  = (const float*)d_in[2];   // [B,G]
    const int*   confs   = (const int*)d_in[3];     // [B,G]

    float* labels_out = (float*)d_out;                              // [B,A]
    float4* boxes_out = (float4*)((float*)d_out + (size_t)NB * NA); // [B,A,4]

    const size_t part_bytes = (size_t)NB * P1 * NG * sizeof(float2); // 512000
    const size_t need = part_bytes + (size_t)NB * NG * sizeof(float);
    if (ws_size >= need) {
        float2* part   = (float2*)d_ws;
        float* highest = (float*)((char*)d_ws + part_bytes);
        dim3 g1(P1, NB), g2(625, NB);
        k_part<<<g1, dim3(1024), 0, stream>>>(anchors, gts, part, highest);
        k_assign2<<<g2, dim3(256), 0, stream>>>(anchors, gts, scores, confs,
                                                highest, labels_out, boxes_out);
    } else {
        float* highest = (float*)d_ws;
        hipMemsetAsync(d_ws, 0, (size_t)NB * NG * sizeof(float), stream);
        dim3 g1(1000, NB), g2(625, NB), blk(256);
        k_gt_highest_fb<<<g1, blk, 0, stream>>>(anchors, gts, highest);
        k_assign2<<<g2, blk, 0, stream>>>(anchors, gts, scores, confs,
                                          highest, labels_out, boxes_out);
    }
}

// Round 6
// 132.680 us; speedup vs baseline: 2.6543x; 1.0030x over previous
//
#include <hip/hip_runtime.h>

// Problem: B=4, A=160000 anchors, G=64 gt boxes.
// outputs (concat flat): labels [B,A] f32, matched_gt_boxes [B,A,4] f32
constexpr int NB = 4;
constexpr int NA = 160000;
constexpr int NG = 64;

// Two-dispatch scheme:
//  k_part   : 1024-thr blocks, anchors+areas LDS-staged, 16 waves x 40
//             anchors with 2-way split accumulators; per-block partial per
//             gt; LAST block per batch (module epoch counter, replay-safe)
//             reduces 250 partials -> haux[b][g] = {garea, highest}.
//  k_assign2: 1 anchor/thread, 2500 blocks; inner loop reads gt box + haux
//             via wave-uniform s_load (scalar pipe, no LDS stalls); LDS only
//             for the cl-indexed epilogue, barrier AFTER the main loop.
constexpr int P1   = 250;         // k_part blocks per batch
constexpr int APB1 = NA / P1;     // 640 anchors per k_part block
constexpr int APW  = 40;          // anchors per wave (16 waves * 40 = 640)

// Module-scope counter: zero-initialized at module load, counted MODULO P1
// -> "last block per batch" works for every graph replay without a memset.
__device__ int g_ctr[NB];

// --- exact-rounding helpers -------------------------------------------------
// contract(off): stop fma fusion that would change rounding vs numpy.
__device__ __forceinline__ float box_area(float x0, float y0, float x1, float y1) {
#pragma clang fp contract(off)
    return (x1 - x0) * (y1 - y0);
}

// inter/denom with the exact op order of the numpy reference; shared by both
// kernels so phase-1's deferred quotient is bit-identical to phase-2's.
__device__ __forceinline__ void inter_denom(float gx0, float gy0, float gx1, float gy1, float garea,
                                            float ax0, float ay0, float ax1, float ay1, float aarea,
                                            float& inter, float& denom) {
#pragma clang fp contract(off)
    float ltx = fmaxf(gx0, ax0);
    float lty = fmaxf(gy0, ay0);
    float rbx = fminf(gx1, ax1);
    float rby = fminf(gy1, ay1);
    float w = fmaxf(rbx - ltx, 0.0f);
    float h = fmaxf(rby - lty, 0.0f);
    inter = w * h;
    float s = garea + aarea;        // numpy: area_gt + area_anchor
    denom = s - inter;
}

// exact comparison  i1/d1 > i2/d2  (all >= 0, d > 0), pure f32:
// FMA two-product gives the EXACT products p+e; ordering decided on the
// rounded products, ties broken on the exact tails (real-number ordering).
// Harness-validated bit-exact (absmax = 0.0, rounds 1-5).
__device__ __forceinline__ bool frac_gt(float i1, float d1, float i2, float d2) {
#pragma clang fp contract(off)
    float p1 = i1 * d2;
    float p2 = i2 * d1;
    float e1 = fmaf(i1, d2, -p1);
    float e2 = fmaf(i2, d1, -p2);
    return (p1 > p2) || ((p1 == p2) && (e1 > e2));
}

// Correctly-rounded f32 divide for our operand range (d in [16, ~5.7e4],
// n in [0, ~1.6e4]): the numerical core LLVM emits for `/` (rcp + NR + 2
// exact-residual FMA corrections) minus div_scale/div_fmas/div_fixup —
// bit-identical results (harness-validated rounds 1-5), no VCC dependency.
__device__ __forceinline__ float div_rn(float n, float d) {
    float y = __builtin_amdgcn_rcpf(d);
    float e = fmaf(-d, y, 1.0f);
    y = fmaf(e, y, y);
    float q = n * y;
    float r = fmaf(-d, q, n);
    q = fmaf(r, y, q);
    float r2 = fmaf(-d, q, n);
    return fmaf(r2, y, q);
}

// pack/unpack float2 <-> u64 for agent-scope 8B atomics
__device__ __forceinline__ unsigned long long pack2(float x, float y) {
    return (unsigned long long)__float_as_uint(x) |
           ((unsigned long long)__float_as_uint(y) << 32);
}
__device__ __forceinline__ void unpack2(unsigned long long u, float& x, float& y) {
    x = __uint_as_float((unsigned)(u & 0xffffffffu));
    y = __uint_as_float((unsigned)(u >> 32));
}

// --- kernel 1: per-gt max; last block per batch finalizes haux --------------
// grid (P1, NB), block 1024 = 16 waves, launch_bounds(1024,8): VGPR cap 64,
// 2 blocks/CU target. Anchor AREAS precomputed at staging (-3 instrs/anchor);
// 2-way split accumulators halve the loop-carried frac_gt chain (only the
// max VALUE is needed per gt, so merge order is irrelevant).
__global__ __launch_bounds__(1024, 8) void k_part(
        const float* __restrict__ anchors, const float* __restrict__ gts,
        float2* __restrict__ part /* [NB][P1][NG] */,
        float2* __restrict__ haux /* [NB][NG] = {garea, highest} */) {
    __shared__ float4 sa[APB1];                     // 640 anchors, 10 KB
    __shared__ float  sar[APB1];                    // areas, 2.5 KB
    __shared__ float pi[16][NG], pd[16][NG];        // 8 KB (reused by reducer)
    __shared__ int s_old;

    const int b = blockIdx.y;
    const int j = blockIdx.x;
    const int lane = threadIdx.x & 63;
    const int wid = __builtin_amdgcn_readfirstlane(threadIdx.x >> 6);

    const float4* __restrict__ anc =
        reinterpret_cast<const float4*>(anchors) + (size_t)b * NA;
    if (threadIdx.x < APB1) {
        float4 v = anc[j * APB1 + threadIdx.x];     // coalesced burst
        sa[threadIdx.x]  = v;
        sar[threadIdx.x] = box_area(v.x, v.y, v.z, v.w);
    }

    float4 g = reinterpret_cast<const float4*>(gts)[b * NG + lane];
    float garea = box_area(g.x, g.y, g.z, g.w);
    __syncthreads();

    const int base = wid * APW;
    float bi0 = 0.0f, bd0 = 1.0f;                   // even-anchor chain
    float bi1 = 0.0f, bd1 = 1.0f;                   // odd-anchor chain
#pragma unroll 4
    for (int i = 0; i < APW; i += 2) {
        float4 a0 = sa[base + i];                   // uniform -> broadcast
        float  aa0 = sar[base + i];
        float4 a1 = sa[base + i + 1];
        float  aa1 = sar[base + i + 1];
        float i0, d0, i1, d1;
        inter_denom(g.x, g.y, g.z, g.w, garea, a0.x, a0.y, a0.z, a0.w, aa0, i0, d0);
        inter_denom(g.x, g.y, g.z, g.w, garea, a1.x, a1.y, a1.z, a1.w, aa1, i1, d1);
        if (frac_gt(i0, d0, bi0, bd0)) { bi0 = i0; bd0 = d0; }
        if (frac_gt(i1, d1, bi1, bd1)) { bi1 = i1; bd1 = d1; }
    }
    if (frac_gt(bi1, bd1, bi0, bd0)) { bi0 = bi1; bd0 = bd1; }

    pi[wid][lane] = bi0;
    pd[wid][lane] = bd0;
    __syncthreads();
    if (threadIdx.x < NG) {
        float ci = pi[0][threadIdx.x], cd = pd[0][threadIdx.x];
#pragma unroll
        for (int wv = 1; wv < 16; ++wv) {
            float ni = pi[wv][threadIdx.x], nd = pd[wv][threadIdx.x];
            if (frac_gt(ni, nd, ci, cd)) { ci = ni; cd = nd; }
        }
        // agent-scope publish: cross-XCD-coherent for the reducer block
        __hip_atomic_store(
            reinterpret_cast<unsigned long long*>(
                &part[((size_t)b * P1 + j) * NG + threadIdx.x]),
            pack2(ci, cd), __ATOMIC_RELAXED, __HIP_MEMORY_SCOPE_AGENT);
    }
    __syncthreads();                // drains the stores (waitcnt before barrier)
    if (threadIdx.x == 0) {
        __threadfence();            // device-scope release before the count
        s_old = atomicAdd(&g_ctr[b], 1);
    }
    __syncthreads();
    if ((s_old % P1) != P1 - 1) return;

    // ---- last block for batch b: reduce 250 partials -> haux[b][g] ---------
    {
        const int gi = threadIdx.x & 63;
        const int c  = threadIdx.x >> 6;            // 16 chunks
        float ci = 0.0f, cd = 1.0f;
#pragma unroll 4
        for (int p = c; p < P1; p += 16) {
            unsigned long long u = __hip_atomic_load(
                reinterpret_cast<const unsigned long long*>(
                    &part[((size_t)b * P1 + p) * NG + gi]),
                __ATOMIC_RELAXED, __HIP_MEMORY_SCOPE_AGENT);
            float ni, nd;
            unpack2(u, ni, nd);
            if (frac_gt(ni, nd, ci, cd)) { ci = ni; cd = nd; }
        }
        pi[c][gi] = ci;
        pd[c][gi] = cd;
    }
    __syncthreads();
    if (threadIdx.x < NG) {
        float ci = pi[0][threadIdx.x], cd = pd[0][threadIdx.x];
#pragma unroll
        for (int wv = 1; wv < 16; ++wv) {
            float ni = pi[wv][threadIdx.x], nd = pd[wv][threadIdx.x];
            if (frac_gt(ni, nd, ci, cd)) { ci = ni; cd = nd; }
        }
        float4 gv = reinterpret_cast<const float4*>(gts)[b * NG + threadIdx.x];
        // plain store: inter-dispatch coherence covers k_assign2's reads
        haux[b * NG + threadIdx.x] =
            make_float2(box_area(gv.x, gv.y, gv.z, gv.w), div_rn(ci, cd));
    }
}

// --- kernel 2: per-anchor match + labels (scalar-pipe gt reads) -------------
// grid (625, NB), block 256, ONE anchor per thread. Inner loop reads gt box
// (s_load_dwordx4) and {garea, highest} (s_load_dwordx2) with wave-uniform
// addresses — scalar pipe prefetches far ahead, zero LDS waits in the loop.
// LDS staging is only for the cl-indexed epilogue; its barrier sits AFTER
// the main loop so staging latency hides under ~3000 cycles of compute.
__global__ __launch_bounds__(256, 8) void k_assign2(
        const float* __restrict__ anchors, const float* __restrict__ gts,
        const float* __restrict__ scores, const int* __restrict__ confs,
        const float2* __restrict__ haux,
        float* __restrict__ labels_out, float4* __restrict__ boxes_out) {
    __shared__ float4 sg[NG];       // gt box (epilogue only)
    __shared__ float  ssc[NG];
    __shared__ int    scf[NG];

    const int b = blockIdx.y;
    if (threadIdx.x < NG) {
        const int gi = threadIdx.x;
        sg[gi]  = reinterpret_cast<const float4*>(gts)[b * NG + gi];
        ssc[gi] = scores[b * NG + gi];
        scf[gi] = confs[b * NG + gi];
    }
    // NO barrier here: main loop doesn't touch LDS.

    const int ai = blockIdx.x * 256 + threadIdx.x;  // 0..159999 exactly
    const float4* __restrict__ anc =
        reinterpret_cast<const float4*>(anchors) + (size_t)b * NA;
    float4 av = anc[ai];
    float aarea = box_area(av.x, av.y, av.z, av.w);

    const float4* __restrict__ gt4 =
        reinterpret_cast<const float4*>(gts) + b * NG;
    const float2* __restrict__ hx = haux + b * NG;

    float best = -1.0f;             // all-zero row -> argmax 0 (first max)
    int   matches = 0;
    bool  lowq = false;
#pragma unroll 8
    for (int g = 0; g < NG; ++g) {
        float4 gb = gt4[g];                         // uniform -> s_load_dwordx4
        float2 ah = hx[g];                          // uniform -> s_load_dwordx2
        float inter, denom;
        inter_denom(gb.x, gb.y, gb.z, gb.w, ah.x,
                    av.x, av.y, av.z, av.w, aarea, inter, denom);
        float v = div_rn(inter, denom);             // bit-exact IEEE quotient
        if (v > best) { best = v; matches = g; }    // strict > keeps FIRST max
        lowq |= (v == ah.y);                        // bit-exact equality
    }

    int m    = (best < 0.3f) ? -1 : ((best < 0.7f) ? -2 : matches);
    int midx = lowq ? matches : m;
    int cl   = (midx < 0) ? 0 : midx;

    __syncthreads();                // staging issued ~3000 cycles ago
    float4 mg = sg[cl];
    float  sc = ssc[cl];
    int    cf = scf[cl];

    bool pos = (midx >= 0);
    float lab = pos ? 1.0f : 0.0f;
    lab = fminf(lab, sc);
    if (midx == -1) lab = 0.0f;
    if (midx == -2) lab = -1.0f;
    if (sc < 1.0f && pos) lab = -1.0f;
    if (cf == 0 && pos) lab = -1.0f;

    labels_out[(size_t)b * NA + ai] = lab;
    boxes_out[(size_t)b * NA + ai] = mg;
}

// --- fallback (ws too small): memset + atomicMax + LDS-loop assign ----------
__global__ __launch_bounds__(256) void k_gt_highest_fb(
        const float* __restrict__ anchors, const float* __restrict__ gts,
        float* __restrict__ highest /* [B*G], pre-zeroed */) {
    const int b = blockIdx.y;
    const int lane = threadIdx.x & 63;
    const int wid = __builtin_amdgcn_readfirstlane(threadIdx.x >> 6);

    const float4* __restrict__ anc =
        reinterpret_cast<const float4*>(anchors) + (size_t)b * NA;
    float4 g = reinterpret_cast<const float4*>(gts)[b * NG + lane];
    float garea = box_area(g.x, g.y, g.z, g.w);

    const int base = blockIdx.x * 160 + wid * 40;
    float bi = 0.0f, bd = 1.0f;
#pragma unroll 8
    for (int i = 0; i < 40; ++i) {
        float4 a = anc[base + i];
        float aarea = box_area(a.x, a.y, a.z, a.w);
        float inter, denom;
        inter_denom(g.x, g.y, g.z, g.w, garea, a.x, a.y, a.z, a.w, aarea,
                    inter, denom);
        if (frac_gt(inter, denom, bi, bd)) { bi = inter; bd = denom; }
    }

    __shared__ float pi[4][NG], pd[4][NG];
    pi[wid][lane] = bi;
    pd[wid][lane] = bd;
    __syncthreads();
    if (threadIdx.x < NG) {
        float ci = pi[0][threadIdx.x], cd = pd[0][threadIdx.x];
#pragma unroll
        for (int wv = 1; wv < 4; ++wv) {
            float ni = pi[wv][threadIdx.x], nd = pd[wv][threadIdx.x];
            if (frac_gt(ni, nd, ci, cd)) { ci = ni; cd = nd; }
        }
        atomicMax(reinterpret_cast<int*>(&highest[b * NG + threadIdx.x]),
                  __float_as_int(div_rn(ci, cd)));
    }
}

__global__ __launch_bounds__(256) void k_assign_fb(
        const float* __restrict__ anchors, const float* __restrict__ gts,
        const float* __restrict__ scores, const int* __restrict__ confs,
        const float* __restrict__ highest,
        float* __restrict__ labels_out, float4* __restrict__ boxes_out) {
    __shared__ float4 sg[NG];
    __shared__ float2 sah[NG];
    __shared__ float  ssc[NG];
    __shared__ int    scf[NG];

    const int b = blockIdx.y;
    if (threadIdx.x < NG) {
        const int gi = threadIdx.x;
        float4 gv = reinterpret_cast<const float4*>(gts)[b * NG + gi];
        sg[gi]  = gv;
        sah[gi] = make_float2(box_area(gv.x, gv.y, gv.z, gv.w),
                              highest[b * NG + gi]);
        ssc[gi] = scores[b * NG + gi];
        scf[gi] = confs[b * NG + gi];
    }
    __syncthreads();

    const int ai = blockIdx.x * 256 + threadIdx.x;
    const float4* __restrict__ anc =
        reinterpret_cast<const float4*>(anchors) + (size_t)b * NA;
    float4 av = anc[ai];
    float aarea = box_area(av.x, av.y, av.z, av.w);

    float best = -1.0f;
    int   matches = 0;
    bool  lowq = false;
#pragma unroll 4
    for (int g = 0; g < NG; ++g) {
        float4 gb = sg[g];
        float2 ah = sah[g];
        float inter, denom;
        inter_denom(gb.x, gb.y, gb.z, gb.w, ah.x,
                    av.x, av.y, av.z, av.w, aarea, inter, denom);
        float v = div_rn(inter, denom);
        if (v > best) { best = v; matches = g; }
        lowq |= (v == ah.y);
    }

    int m    = (best < 0.3f) ? -1 : ((best < 0.7f) ? -2 : matches);
    int midx = lowq ? matches : m;
    int cl   = (midx < 0) ? 0 : midx;

    float4 mg = sg[cl];
    float  sc = ssc[cl];
    int    cf = scf[cl];

    bool pos = (midx >= 0);
    float lab = pos ? 1.0f : 0.0f;
    lab = fminf(lab, sc);
    if (midx == -1) lab = 0.0f;
    if (midx == -2) lab = -1.0f;
    if (sc < 1.0f && pos) lab = -1.0f;
    if (cf == 0 && pos) lab = -1.0f;

    labels_out[(size_t)b * NA + ai] = lab;
    boxes_out[(size_t)b * NA + ai] = mg;
}

extern "C" void kernel_launch(void* const* d_in, const int* in_sizes, int n_in,
                              void* d_out, int out_size, void* d_ws, size_t ws_size,
                              hipStream_t stream) {
    const float* anchors = (const float*)d_in[0];   // [B,A,4]
    const float* gts     = (const float*)d_in[1];   // [B,G,4]
    const float* scores  = (const float*)d_in[2];   // [B,G]
    const int*   confs   = (const int*)d_in[3];     // [B,G]

    float* labels_out = (float*)d_out;                              // [B,A]
    float4* boxes_out = (float4*)((float*)d_out + (size_t)NB * NA); // [B,A,4]

    const size_t part_bytes = (size_t)NB * P1 * NG * sizeof(float2); // 512000
    const size_t need = part_bytes + (size_t)NB * NG * sizeof(float2);
    if (ws_size >= need) {
        float2* part = (float2*)d_ws;
        float2* haux = (float2*)((char*)d_ws + part_bytes);
        dim3 g1(P1, NB), g2(625, NB);
        k_part<<<g1, dim3(1024), 0, stream>>>(anchors, gts, part, haux);
        k_assign2<<<g2, dim3(256), 0, stream>>>(anchors, gts, scores, confs,
                                                haux, labels_out, boxes_out);
    } else {
        float* highest = (float*)d_ws;
        hipMemsetAsync(d_ws, 0, (size_t)NB * NG * sizeof(float), stream);
        dim3 g1(1000, NB), g2(625, NB), blk(256);
        k_gt_highest_fb<<<g1, blk, 0, stream>>>(anchors, gts, highest);
        k_assign_fb<<<g2, blk, 0, stream>>>(anchors, gts, scores, confs,
                                            highest, labels_out, boxes_out);
    }
}